// Round 20
// baseline (89.974 us; speedup 1.0000x reference)
//
#include <hip/hip_runtime.h>
#include <hip/hip_bf16.h>

// Problem constants
#define BPn   2048      // B*P
#define NEn   400
#define NT    51200     // (2048/4)*(400/4) 16-row tiles (4bp x 4e)
#define NBLK  512       // 2 blocks/CU (640-thr / 10-wave blocks)
#define NWAVES 5120     // 512 * 10; NT/NWAVES = 10 tiles/wave exactly

typedef __attribute__((ext_vector_type(8)))  short  short8;
typedef __attribute__((ext_vector_type(4)))  float  f32x4v;

__device__ __forceinline__ unsigned short bf16c(float x) {
  return __builtin_bit_cast(unsigned short, __float2bfloat16(x));
}

// async global->LDS, 16B per lane. Global src per-lane, LDS dest uniform base + lane*16.
__device__ __forceinline__ void glds16(const void* g, void* l) {
  __builtin_amdgcn_global_load_lds(
      (const __attribute__((address_space(1))) unsigned int*)g,
      (__attribute__((address_space(3))) unsigned int*)l, 16, 0, 0);
}

// ---------------- prep: hp[2048][128] and he[400][128] (f32) ----------------
__global__ void prep_emb(const int* __restrict__ z_j, const int* __restrict__ z_k,
                         const float* __restrict__ e_feat, const float* __restrict__ z_emb,
                         const float* __restrict__ W1, const float* __restrict__ b1,
                         float* __restrict__ hp, float* __restrict__ he)
{
  const int t = threadIdx.x;           // 0..127
  const int bidx = blockIdx.x;
  if (bidx < BPn) {
    const int zj = z_j[bidx], zk = z_k[bidx];
    const float* ej = z_emb + zj * 64;
    const float* ek = z_emb + zk * 64;
    float acc = b1[t];
    #pragma unroll 8
    for (int k = 0; k < 64; ++k) acc += ej[k] * W1[k * 128 + t];
    #pragma unroll 8
    for (int k = 0; k < 64; ++k) acc += ek[k] * W1[(64 + k) * 128 + t];
    hp[bidx * 128 + t] = acc;
  } else {
    const int e = bidx - BPn;          // 0..399
    float acc = 0.0f;
    #pragma unroll 8
    for (int k = 0; k < 32; ++k) acc += e_feat[e * 32 + k] * W1[(128 + k) * 128 + t];
    he[e * 128 + t] = acc;
  }
}

// ---------------- prep: weights to bf16 fragments ----------------
// w2f (A-slot, COLUMN-PERMUTED): w2f[((g*4+ks)*64+l)*8+j] =
//   W2[ks*32 + (l>>4)*8 + j][ 32*(g>>1) + 8*((l&15)>>2) + 4*(g&1) + ((l&15)&3) ]
// Makes GEMM1's D-fragment directly reusable as GEMM2's B-operand (lane-local).
// w3f: w3f[(ks*64+l)*8+j] = W3[ks*32+(l>>4)*8+j][l&15]
__global__ void prep_w(const float* __restrict__ W2, const float* __restrict__ W3,
                       unsigned short* __restrict__ w2f, unsigned short* __restrict__ w3f)
{
  const int idx = blockIdx.x * 256 + threadIdx.x;
  if (idx < 16384) {
    const int j  = idx & 7;
    const int l  = (idx >> 3) & 63;
    const int ks = (idx >> 9) & 3;
    const int g  = idx >> 11;
    const int k  = ks * 32 + (l >> 4) * 8 + j;
    const int i  = l & 15;
    const int n  = 32 * (g >> 1) + 8 * (i >> 2) + 4 * (g & 1) + (i & 3);
    w2f[idx] = bf16c(W2[k * 128 + n]);
  }
  if (idx < 2048) {
    const int ks = idx >> 9;
    const int l  = (idx >> 3) & 63;
    const int j  = idx & 7;
    const int k  = ks * 32 + ((l >> 4) & 3) * 8 + j;
    w3f[idx] = bf16c(W3[k * 16 + (l & 15)]);
  }
}

// ---------------- fused main: wave-autonomous, 10-wave blocks, 16-row tiles ----------------
// Per wave: 16-row tile (4bp x 4e), acc[8] = 32 VGPRs (half of r17) -> target VGPR <= 102
// -> 5 waves/SIMD (20 waves/CU at 2 blocks). Zero in-loop barriers; stride tile order.
// Both hp and he slabs XOR-swizzled by (row&3)<<4 (4 concurrent rows -> 2-way banks).
__global__ __launch_bounds__(640, 5)
void fused_main(const float* __restrict__ hp, const float* __restrict__ he,
                const unsigned short* __restrict__ w2f, const unsigned short* __restrict__ w3f,
                const float* __restrict__ b2, const float* __restrict__ b3,
                float* __restrict__ out)
{
  __shared__ __align__(16) unsigned short ldsW[16384];   // 32KB: W2 frag table (permuted)
  __shared__ __align__(16) float          ldsS[10240];   // 10 waves x 4KB: hp 4 rows | he 4 rows
  __shared__ __align__(16) float          ldsB2[128];    // 512B: b2 (keeps it out of VGPRs)
  const int t    = threadIdx.x;       // 0..639
  const int lane = t & 63;
  const int wid  = t >> 6;            // 0..9
  const int r    = lane & 15;         // tile row / GEMM2 out-row lane
  const int o    = lane >> 4;         // k-octet / out-col-quad selector
  const int bl   = r >> 2;            // hp row in tile (0..3)
  const int el   = r & 3;             // he row in tile (0..3)
  const int swzP = bl << 4;
  const int swzE = el << 4;

  // ---- stage W2 frag table + b2 (once per block) ----
  for (int i = t; i < 2048; i += 640)
    ((uint4*)ldsW)[i] = ((const uint4*)w2f)[i];
  if (t < 128) ldsB2[t] = b2[t];
  __syncthreads();                    // the only barrier

  // W3 fragments (A-slot), loop-invariant
  short8 w3r[4];
  #pragma unroll
  for (int ks = 0; ks < 4; ++ks)
    w3r[ks] = *(const short8*)(w3f + (ks * 64 + lane) * 8);
  const f32x4v b3v = *(const f32x4v*)(b3 + o * 4);

  char* Sb = (char*)(ldsS + wid * 1024);   // 4KB per wave

  // staging offsets: dest row_d gets src bytes (lo16 ^ (row_d<<4)) of that row (involution)
  const int rowd = lane >> 5;              // 0/1 within each 1KB chunk
  const int lo16 = (lane & 31) * 16;
  const int off0 = rowd * 512       + (lo16 ^ (rowd << 4));        // rows 0,1
  const int off1 = (2 + rowd) * 512 + (lo16 ^ ((2 + rowd) << 4));  // rows 2,3

  #define STAGE(b0_, e0_) do { \
    glds16((const char*)hp + (size_t)(b0_) * 512 + off0, Sb); \
    glds16((const char*)hp + (size_t)(b0_) * 512 + off1, Sb + 1024); \
    glds16((const char*)he + (size_t)(e0_) * 512 + off0, Sb + 2048); \
    glds16((const char*)he + (size_t)(e0_) * 512 + off1, Sb + 3072); \
  } while (0)

  const int gw = blockIdx.x * 10 + wid;    // 0..5119; tiles gw, gw+5120, ... (10 total)
  int tile = gw;
  {
    const unsigned tbp = (unsigned)(((unsigned long long)(unsigned)tile * 2748779070ull) >> 38); // /100
    const int te = tile - (int)tbp * 100;
    STAGE(tbp * 4, te * 4);
  }
  asm volatile("s_waitcnt vmcnt(0)" ::: "memory");
  __builtin_amdgcn_sched_barrier(0);

  const char* hpB = Sb + bl * 512;
  const char* heB = Sb + 2048 + el * 512;

  #pragma unroll 1
  for (int it = 0; it < 10; ++it) {
    const unsigned tbp = (unsigned)(((unsigned long long)(unsigned)tile * 2748779070ull) >> 38);
    const int te = tile - (int)tbp * 100;
    const int b0 = (int)tbp * 4;
    const int e0 = te * 4;

    // ---- acc init = b2 fragment from LDS (folds bias into MFMA C-input) ----
    f32x4v acc[8];
    #pragma unroll
    for (int g = 0; g < 8; ++g)
      acc[g] = *(const f32x4v*)(ldsB2 + (32 * (g >> 1) + 4 * (g & 1) + 8 * o));

    // ---- fused BUILD + GEMM1 (independent per-element silu) ----
    #pragma unroll
    for (int ks = 0; ks < 4; ++ks) {
      const int x = ks * 128 + o * 32;
      const f32x4v a0 = *(const f32x4v*)(hpB + (x ^ swzP));
      const f32x4v a1 = *(const f32x4v*)(hpB + ((x + 16) ^ swzP));
      const f32x4v g0 = *(const f32x4v*)(heB + (x ^ swzE));
      const f32x4v g1 = *(const f32x4v*)(heB + ((x + 16) ^ swzE));
      const f32x4v x0 = a0 + g0, x1 = a1 + g1;
      f32x4v d0, d1;
      #pragma unroll
      for (int j = 0; j < 4; ++j) {
        d0[j] = __builtin_amdgcn_exp2f(x0[j] * -1.44269504f);
        d1[j] = __builtin_amdgcn_exp2f(x1[j] * -1.44269504f);
      }
      d0 += 1.0f; d1 += 1.0f;
      f32x4v s0, s1;
      #pragma unroll
      for (int j = 0; j < 4; ++j) {
        s0[j] = __builtin_amdgcn_rcpf(d0[j]); s1[j] = __builtin_amdgcn_rcpf(d1[j]);
      }
      s0 *= x0; s1 *= x1;
      short8 fA;
      #pragma unroll
      for (int j = 0; j < 4; ++j) {
        fA[j] = (short)bf16c(s0[j]); fA[4 + j] = (short)bf16c(s1[j]);
      }
      #pragma unroll
      for (int g = 0; g < 8; ++g) {
        const short8 wf = *(const short8*)((const char*)ldsW + (((g * 4 + ks) << 10) | (lane << 4)));
        acc[g] = __builtin_amdgcn_mfma_f32_16x16x32_bf16(wf, fA, acc[g], 0, 0, 0);
      }
    }

    // ---- stage next tile (slab reads retired; glds lands under WB/GEMM2/store) ----
    asm volatile("s_waitcnt lgkmcnt(0)" ::: "memory");
    __builtin_amdgcn_sched_barrier(0);
    const bool have_next = (it < 9);
    const int nxt = tile + NWAVES;
    if (have_next) {
      const unsigned ntbp = (unsigned)(((unsigned long long)(unsigned)nxt * 2748779070ull) >> 38);
      const int nte = nxt - (int)ntbp * 100;
      STAGE(ntbp * 4, nte * 4);
    }
    __builtin_amdgcn_sched_barrier(0);

    // ---- WB-silu (in-reg) -> bfrag2 -> GEMM2 -> nt store ----
    short8 bf2[4];
    #pragma unroll
    for (int ks2 = 0; ks2 < 4; ++ks2) {
      const f32x4v y0 = acc[2 * ks2];
      const f32x4v y1 = acc[2 * ks2 + 1];
      f32x4v d0, d1;
      #pragma unroll
      for (int j = 0; j < 4; ++j) {
        d0[j] = __builtin_amdgcn_exp2f(y0[j] * -1.44269504f);
        d1[j] = __builtin_amdgcn_exp2f(y1[j] * -1.44269504f);
      }
      d0 += 1.0f; d1 += 1.0f;
      f32x4v s0, s1;
      #pragma unroll
      for (int j = 0; j < 4; ++j) {
        s0[j] = __builtin_amdgcn_rcpf(d0[j]); s1[j] = __builtin_amdgcn_rcpf(d1[j]);
      }
      s0 *= y0; s1 *= y1;
      #pragma unroll
      for (int j = 0; j < 4; ++j) {
        bf2[ks2][j]     = (short)bf16c(s0[j]);
        bf2[ks2][4 + j] = (short)bf16c(s1[j]);
      }
    }
    f32x4v acc2 = {};
    #pragma unroll
    for (int ks2 = 0; ks2 < 4; ++ks2)
      acc2 = __builtin_amdgcn_mfma_f32_16x16x32_bf16(w3r[ks2], bf2[ks2], acc2, 0, 0, 0);

    const int grow = (b0 + (r >> 2)) * 400 + e0 + (r & 3);
    f32x4v ov = acc2 + b3v;
    __builtin_nontemporal_store(ov, (f32x4v*)(out + grow * 16 + o * 4));

    tile = nxt;
    if (have_next) {
      // 4 glds (older) + 1 store outstanding -> vmcnt(1) drains all glds
      asm volatile("s_waitcnt vmcnt(1)" ::: "memory");
      __builtin_amdgcn_sched_barrier(0);
    }
  }
  #undef STAGE
}

extern "C" void kernel_launch(void* const* d_in, const int* in_sizes, int n_in,
                              void* d_out, int out_size, void* d_ws, size_t ws_size,
                              hipStream_t stream) {
  const int*   z_j    = (const int*)d_in[0];
  const int*   z_k    = (const int*)d_in[1];
  const float* e_feat = (const float*)d_in[2];
  const float* z_emb  = (const float*)d_in[3];
  const float* W1     = (const float*)d_in[4];
  const float* b1     = (const float*)d_in[5];
  const float* W2     = (const float*)d_in[6];
  const float* b2     = (const float*)d_in[7];
  const float* W3     = (const float*)d_in[8];
  const float* b3     = (const float*)d_in[9];
  float* out = (float*)d_out;
  char*  ws  = (char*)d_ws;

  float*          hp   = (float*)(ws);                     // 1 MB
  float*          he   = (float*)(ws + 0x100000);          // 200 KB
  unsigned short* w2f  = (unsigned short*)(ws + 0x140000); // 32 KB
  unsigned short* w3f  = (unsigned short*)(ws + 0x148000); // 4 KB

  hipLaunchKernelGGL(prep_emb, dim3(BPn + NEn), dim3(128), 0, stream,
                     z_j, z_k, e_feat, z_emb, W1, b1, hp, he);
  hipLaunchKernelGGL(prep_w, dim3(64), dim3(256), 0, stream, W2, W3, w2f, w3f);
  hipLaunchKernelGGL(fused_main, dim3(NBLK), dim3(640), 0, stream,
                     hp, he, w2f, w3f, b2, b3, out);
}

// Round 21
// 82.038 us; speedup vs baseline: 1.0967x; 1.0967x over previous
//
#include <hip/hip_runtime.h>
#include <hip/hip_bf16.h>

// Problem constants
#define BPn   2048      // B*P
#define NEn   400
#define NT    25600     // (2048/4)*(400/8) 32-row tiles (4bp x 8e)
#define NBLK  512       // 2 blocks/CU (512-thr / 8-wave blocks)
#define NWAVES 4096     // 512 * 8

typedef __attribute__((ext_vector_type(8)))  short  short8;
typedef __attribute__((ext_vector_type(4)))  float  f32x4v;

__device__ __forceinline__ unsigned short bf16c(float x) {
  return __builtin_bit_cast(unsigned short, __float2bfloat16(x));
}

// async global->LDS, 16B per lane. Global src per-lane, LDS dest uniform base + lane*16.
__device__ __forceinline__ void glds16(const void* g, void* l) {
  __builtin_amdgcn_global_load_lds(
      (const __attribute__((address_space(1))) unsigned int*)g,
      (__attribute__((address_space(3))) unsigned int*)l, 16, 0, 0);
}

// ---------------- prep: hp[2048][128] and he[400][128] (f32) ----------------
__global__ void prep_emb(const int* __restrict__ z_j, const int* __restrict__ z_k,
                         const float* __restrict__ e_feat, const float* __restrict__ z_emb,
                         const float* __restrict__ W1, const float* __restrict__ b1,
                         float* __restrict__ hp, float* __restrict__ he)
{
  const int t = threadIdx.x;           // 0..127
  const int bidx = blockIdx.x;
  if (bidx < BPn) {
    const int zj = z_j[bidx], zk = z_k[bidx];
    const float* ej = z_emb + zj * 64;
    const float* ek = z_emb + zk * 64;
    float acc = b1[t];
    #pragma unroll 8
    for (int k = 0; k < 64; ++k) acc += ej[k] * W1[k * 128 + t];
    #pragma unroll 8
    for (int k = 0; k < 64; ++k) acc += ek[k] * W1[(64 + k) * 128 + t];
    hp[bidx * 128 + t] = acc;
  } else {
    const int e = bidx - BPn;          // 0..399
    float acc = 0.0f;
    #pragma unroll 8
    for (int k = 0; k < 32; ++k) acc += e_feat[e * 32 + k] * W1[(128 + k) * 128 + t];
    he[e * 128 + t] = acc;
  }
}

// ---------------- prep: weights to bf16 fragments ----------------
// w2f (A-slot, COLUMN-PERMUTED): w2f[((g*4+ks)*64+l)*8+j] =
//   W2[ks*32 + (l>>4)*8 + j][ 32*(g>>1) + 8*((l&15)>>2) + 4*(g&1) + ((l&15)&3) ]
// Makes GEMM1's D-fragment directly reusable as GEMM2's B-operand (lane-local).
// w3f: w3f[(ks*64+l)*8+j] = W3[ks*32+(l>>4)*8+j][l&15]
__global__ void prep_w(const float* __restrict__ W2, const float* __restrict__ W3,
                       unsigned short* __restrict__ w2f, unsigned short* __restrict__ w3f)
{
  const int idx = blockIdx.x * 256 + threadIdx.x;
  if (idx < 16384) {
    const int j  = idx & 7;
    const int l  = (idx >> 3) & 63;
    const int ks = (idx >> 9) & 3;
    const int g  = idx >> 11;
    const int k  = ks * 32 + (l >> 4) * 8 + j;
    const int i  = l & 15;
    const int n  = 32 * (g >> 1) + 8 * (i >> 2) + 4 * (g & 1) + (i & 3);
    w2f[idx] = bf16c(W2[k * 128 + n]);
  }
  if (idx < 2048) {
    const int ks = idx >> 9;
    const int l  = (idx >> 3) & 63;
    const int j  = idx & 7;
    const int k  = ks * 32 + ((l >> 4) & 3) * 8 + j;
    w3f[idx] = bf16c(W3[k * 16 + (l & 15)]);
  }
}

// ---------------- fused main: wave-autonomous, 8-wave blocks, zero in-loop barriers ----------------
// r17 structure exactly, plus a tile-SET permutation for tail balance:
//   wave gw executes set s = (gw&3)*1024 + (gw>>2); set s = tiles {s, s+4096, ...}.
// The 1024 seven-tile sets (s<1024) land on gw%4==0 -> exactly 2 per block, 4 per CU
// (r17 concentrated them on blocks 0..127 = 64 CUs -> 1.167x CU imbalance).
// Access pattern per wave is IDENTICAL to r17 (stride-4096 walks).
__global__ __launch_bounds__(512, 2)
void fused_main(const float* __restrict__ hp, const float* __restrict__ he,
                const unsigned short* __restrict__ w2f, const unsigned short* __restrict__ w3f,
                const float* __restrict__ b2, const float* __restrict__ b3,
                float* __restrict__ out)
{
  __shared__ __align__(16) unsigned short ldsW[16384];   // 32KB: W2 frag table (permuted)
  __shared__ __align__(16) float          ldsS[12288];   // 8 waves x 6KB: hp 4 rows | he 8 rows
  const int t    = threadIdx.x;       // 0..511
  const int lane = t & 63;
  const int wid  = t >> 6;            // 0..7
  const int r    = lane & 15;         // tile row within group / GEMM2 out-row lane
  const int o    = lane >> 4;         // k-octet / out-col-quad selector
  const int Rr   = r & 7;             // he row
  const int swzR = Rr << 4;

  // ---- stage W2 frag table (once per block) ----
  for (int i = t; i < 2048; i += 512)
    ((uint4*)ldsW)[i] = ((const uint4*)w2f)[i];
  __syncthreads();                    // the only barrier

  // W3 fragments (A-slot), loop-invariant
  short8 w3r[4];
  #pragma unroll
  for (int ks = 0; ks < 4; ++ks)
    w3r[ks] = *(const short8*)(w3f + (ks * 64 + lane) * 8);
  const f32x4v b3v = *(const f32x4v*)(b3 + o * 4);
  const float* b2o = b2 + 8 * o;

  char* Sb = (char*)(ldsS + wid * 1536);

  // he staging: pre-swizzled source offsets (involution: byte w holds he[row][w ^ (row<<4)])
  int heoff[4];
  #pragma unroll
  for (int i = 0; i < 4; ++i) {
    const int row = 2 * i + (lane >> 5);
    heoff[i] = row * 512 + ((((lane & 31) * 16)) ^ (row << 4));
  }

  #define STAGE(b0_, e0_) do { \
    glds16(hp + (b0_) * 128 + lane * 4,       Sb); \
    glds16(hp + (b0_) * 128 + 256 + lane * 4, Sb + 1024); \
    _Pragma("unroll") \
    for (int i_ = 0; i_ < 4; ++i_) \
      glds16((const char*)he + (e0_) * 512 + heoff[i_], Sb + 2048 + i_ * 1024); \
  } while (0)

  // balanced tile-set permutation (bijection on [0,4096))
  const int gw = blockIdx.x * 8 + wid;            // 0..4095
  int tile = ((gw & 3) << 10) | (gw >> 2);        // starting set id
  {
    const int tbp = (int)(((unsigned)tile * 5243u) >> 18);  // tile/50 exact for tile<25600
    const int te  = tile - tbp * 50;
    STAGE(tbp * 4, te * 8);
  }
  asm volatile("s_waitcnt vmcnt(0)" ::: "memory");
  __builtin_amdgcn_sched_barrier(0);

  const char* heB = Sb + 2048 + Rr * 512;
  const char* hA  = Sb + (r >> 3) * 512;
  const char* hB  = hA + 1024;

  while (true) {
    const int tbp = (int)(((unsigned)tile * 5243u) >> 18);
    const int te  = tile - tbp * 50;
    const int b0  = tbp * 4;
    const int e0  = te * 8;

    // ---- acc init = b2 fragment (folds bias into MFMA C-input) ----
    f32x4v acc0[8], acc1[8];
    #pragma unroll
    for (int g = 0; g < 8; ++g) {
      const f32x4v bv = *(const f32x4v*)(b2o + 32 * (g >> 1) + 4 * (g & 1));
      acc0[g] = bv; acc1[g] = bv;
    }

    // ---- fused BUILD + GEMM1 (independent per-element silu) ----
    #pragma unroll
    for (int ks = 0; ks < 4; ++ks) {
      const int x = ks * 128 + o * 32;
      const f32x4v ge0 = *(const f32x4v*)(heB + ((x)      ^ swzR));
      const f32x4v ge1 = *(const f32x4v*)(heB + ((x + 16) ^ swzR));
      const f32x4v a0  = *(const f32x4v*)(hA + x);
      const f32x4v a1  = *(const f32x4v*)(hA + x + 16);
      const f32x4v c0  = *(const f32x4v*)(hB + x);
      const f32x4v c1  = *(const f32x4v*)(hB + x + 16);
      const f32x4v xA0 = a0 + ge0, xA1 = a1 + ge1;
      const f32x4v xB0 = c0 + ge0, xB1 = c1 + ge1;
      f32x4v dA0, dA1, dB0, dB1;
      #pragma unroll
      for (int j = 0; j < 4; ++j) {
        dA0[j] = __builtin_amdgcn_exp2f(xA0[j] * -1.44269504f);
        dA1[j] = __builtin_amdgcn_exp2f(xA1[j] * -1.44269504f);
        dB0[j] = __builtin_amdgcn_exp2f(xB0[j] * -1.44269504f);
        dB1[j] = __builtin_amdgcn_exp2f(xB1[j] * -1.44269504f);
      }
      dA0 += 1.0f; dA1 += 1.0f; dB0 += 1.0f; dB1 += 1.0f;
      f32x4v sA0, sA1, sB0, sB1;
      #pragma unroll
      for (int j = 0; j < 4; ++j) {
        sA0[j] = __builtin_amdgcn_rcpf(dA0[j]); sA1[j] = __builtin_amdgcn_rcpf(dA1[j]);
        sB0[j] = __builtin_amdgcn_rcpf(dB0[j]); sB1[j] = __builtin_amdgcn_rcpf(dB1[j]);
      }
      sA0 *= xA0; sA1 *= xA1; sB0 *= xB0; sB1 *= xB1;
      short8 fA, fB;
      #pragma unroll
      for (int j = 0; j < 4; ++j) {
        fA[j] = (short)bf16c(sA0[j]); fA[4 + j] = (short)bf16c(sA1[j]);
        fB[j] = (short)bf16c(sB0[j]); fB[4 + j] = (short)bf16c(sB1[j]);
      }
      #pragma unroll
      for (int g = 0; g < 8; ++g) {
        const short8 wf = *(const short8*)((const char*)ldsW + (((g * 4 + ks) << 10) | (lane << 4)));
        acc0[g] = __builtin_amdgcn_mfma_f32_16x16x32_bf16(wf, fA, acc0[g], 0, 0, 0);
        acc1[g] = __builtin_amdgcn_mfma_f32_16x16x32_bf16(wf, fB, acc1[g], 0, 0, 0);
      }
    }

    // ---- stage next tile (slab reads all retired; glds lands under WB/GEMM2/stores) ----
    asm volatile("s_waitcnt lgkmcnt(0)" ::: "memory");
    __builtin_amdgcn_sched_barrier(0);
    const int nxt = tile + NWAVES;
    if (nxt < NT) {
      const int ntbp = (int)(((unsigned)nxt * 5243u) >> 18);
      const int nte  = nxt - ntbp * 50;
      STAGE(ntbp * 4, nte * 8);
    }
    __builtin_amdgcn_sched_barrier(0);

    // ---- per row-group: WB-silu (independent rcp) -> bfrag2 -> GEMM2 -> nt store ----
    #pragma unroll
    for (int G = 0; G < 2; ++G) {
      short8 bf2[4];
      #pragma unroll
      for (int ks2 = 0; ks2 < 4; ++ks2) {
        const f32x4v y0 = G ? acc1[2 * ks2]     : acc0[2 * ks2];
        const f32x4v y1 = G ? acc1[2 * ks2 + 1] : acc0[2 * ks2 + 1];
        f32x4v d0, d1;
        #pragma unroll
        for (int j = 0; j < 4; ++j) {
          d0[j] = __builtin_amdgcn_exp2f(y0[j] * -1.44269504f);
          d1[j] = __builtin_amdgcn_exp2f(y1[j] * -1.44269504f);
        }
        d0 += 1.0f; d1 += 1.0f;
        f32x4v s0, s1;
        #pragma unroll
        for (int j = 0; j < 4; ++j) {
          s0[j] = __builtin_amdgcn_rcpf(d0[j]); s1[j] = __builtin_amdgcn_rcpf(d1[j]);
        }
        s0 *= y0; s1 *= y1;
        #pragma unroll
        for (int j = 0; j < 4; ++j) {
          bf2[ks2][j]     = (short)bf16c(s0[j]);
          bf2[ks2][4 + j] = (short)bf16c(s1[j]);
        }
      }
      f32x4v acc2 = {};
      #pragma unroll
      for (int ks2 = 0; ks2 < 4; ++ks2)
        acc2 = __builtin_amdgcn_mfma_f32_16x16x32_bf16(w3r[ks2], bf2[ks2], acc2, 0, 0, 0);

      const int grow = (b0 + G * 2 + (r >> 3)) * 400 + e0 + Rr;
      f32x4v ov = acc2 + b3v;
      __builtin_nontemporal_store(ov, (f32x4v*)(out + grow * 16 + o * 4));
    }

    if (nxt >= NT) break;
    tile = nxt;
    // staged S(t+1) ready: 6 glds older than the 2 stores -> vmcnt(2) drains all glds
    asm volatile("s_waitcnt vmcnt(2)" ::: "memory");
    __builtin_amdgcn_sched_barrier(0);
  }
  #undef STAGE
}

extern "C" void kernel_launch(void* const* d_in, const int* in_sizes, int n_in,
                              void* d_out, int out_size, void* d_ws, size_t ws_size,
                              hipStream_t stream) {
  const int*   z_j    = (const int*)d_in[0];
  const int*   z_k    = (const int*)d_in[1];
  const float* e_feat = (const float*)d_in[2];
  const float* z_emb  = (const float*)d_in[3];
  const float* W1     = (const float*)d_in[4];
  const float* b1     = (const float*)d_in[5];
  const float* W2     = (const float*)d_in[6];
  const float* b2     = (const float*)d_in[7];
  const float* W3     = (const float*)d_in[8];
  const float* b3     = (const float*)d_in[9];
  float* out = (float*)d_out;
  char*  ws  = (char*)d_ws;

  float*          hp   = (float*)(ws);                     // 1 MB
  float*          he   = (float*)(ws + 0x100000);          // 200 KB
  unsigned short* w2f  = (unsigned short*)(ws + 0x140000); // 32 KB
  unsigned short* w3f  = (unsigned short*)(ws + 0x148000); // 4 KB

  hipLaunchKernelGGL(prep_emb, dim3(BPn + NEn), dim3(128), 0, stream,
                     z_j, z_k, e_feat, z_emb, W1, b1, hp, he);
  hipLaunchKernelGGL(prep_w, dim3(64), dim3(256), 0, stream, W2, W3, w2f, w3f);
  hipLaunchKernelGGL(fused_main, dim3(NBLK), dim3(512), 0, stream,
                     hp, he, w2f, w3f, b2, b3, out);
}

// Round 22
// 75.890 us; speedup vs baseline: 1.1856x; 1.0810x over previous
//
#include <hip/hip_runtime.h>
#include <hip/hip_bf16.h>

// Problem constants
#define BPn   2048      // B*P
#define NEn   400
#define NT    25600     // (2048/4)*(400/8) 32-row tiles (4bp x 8e)
#define NBLK  512       // 2 blocks/CU (512-thr / 8-wave blocks)
#define NWAVES 4096     // 512 * 8

typedef __attribute__((ext_vector_type(8)))  short  short8;
typedef __attribute__((ext_vector_type(4)))  float  f32x4v;

__device__ __forceinline__ unsigned short bf16c(float x) {
  return __builtin_bit_cast(unsigned short, __float2bfloat16(x));
}

// async global->LDS, 16B per lane. Global src per-lane, LDS dest uniform base + lane*16.
__device__ __forceinline__ void glds16(const void* g, void* l) {
  __builtin_amdgcn_global_load_lds(
      (const __attribute__((address_space(1))) unsigned int*)g,
      (__attribute__((address_space(3))) unsigned int*)l, 16, 0, 0);
}

// ---------------- merged prep: hp/he + weight fragments in ONE launch ----------------
// blocks [0,2048): hp rows; [2048,2448): he rows; [2448,2576): w2f/w3f fragments.
// w2f (A-slot, COLUMN-PERMUTED): w2f[((g*4+ks)*64+l)*8+j] =
//   W2[ks*32 + (l>>4)*8 + j][ 32*(g>>1) + 8*((l&15)>>2) + 4*(g&1) + ((l&15)&3) ]
// w3f: w3f[(ks*64+l)*8+j] = W3[ks*32+(l>>4)*8+j][l&15]
__global__ void prep_all(const int* __restrict__ z_j, const int* __restrict__ z_k,
                         const float* __restrict__ e_feat, const float* __restrict__ z_emb,
                         const float* __restrict__ W1, const float* __restrict__ b1,
                         const float* __restrict__ W2, const float* __restrict__ W3,
                         float* __restrict__ hp, float* __restrict__ he,
                         unsigned short* __restrict__ w2f, unsigned short* __restrict__ w3f)
{
  const int t = threadIdx.x;           // 0..127
  const int bidx = blockIdx.x;
  if (bidx < BPn) {
    const int zj = z_j[bidx], zk = z_k[bidx];
    const float* ej = z_emb + zj * 64;
    const float* ek = z_emb + zk * 64;
    float acc = b1[t];
    #pragma unroll 8
    for (int k = 0; k < 64; ++k) acc += ej[k] * W1[k * 128 + t];
    #pragma unroll 8
    for (int k = 0; k < 64; ++k) acc += ek[k] * W1[(64 + k) * 128 + t];
    hp[bidx * 128 + t] = acc;
  } else if (bidx < BPn + NEn) {
    const int e = bidx - BPn;          // 0..399
    float acc = 0.0f;
    #pragma unroll 8
    for (int k = 0; k < 32; ++k) acc += e_feat[e * 32 + k] * W1[(128 + k) * 128 + t];
    he[e * 128 + t] = acc;
  } else {
    const int idx = (bidx - BPn - NEn) * 128 + t;   // 0..16383
    {
      const int j  = idx & 7;
      const int l  = (idx >> 3) & 63;
      const int ks = (idx >> 9) & 3;
      const int g  = idx >> 11;
      const int k  = ks * 32 + (l >> 4) * 8 + j;
      const int i  = l & 15;
      const int n  = 32 * (g >> 1) + 8 * (i >> 2) + 4 * (g & 1) + (i & 3);
      w2f[idx] = bf16c(W2[k * 128 + n]);
    }
    if (idx < 2048) {
      const int ks = idx >> 9;
      const int l  = (idx >> 3) & 63;
      const int j  = idx & 7;
      const int k  = ks * 32 + ((l >> 4) & 3) * 8 + j;
      w3f[idx] = bf16c(W3[k * 16 + (l & 15)]);
    }
  }
}

// ---------------- fused main: wave-autonomous, 8-wave blocks, zero in-loop barriers ----------------
// r17 structure exactly (stride-4096 tile sets, unpaired rcp, 512-thr blocks) plus
// s_setprio(1) around MFMA clusters: waves drift freely (no barriers) -> the attn-like
// regime where setprio measurably helps (wave's MFMA preempts other waves' trans issue).
__global__ __launch_bounds__(512, 2)
void fused_main(const float* __restrict__ hp, const float* __restrict__ he,
                const unsigned short* __restrict__ w2f, const unsigned short* __restrict__ w3f,
                const float* __restrict__ b2, const float* __restrict__ b3,
                float* __restrict__ out)
{
  __shared__ __align__(16) unsigned short ldsW[16384];   // 32KB: W2 frag table (permuted)
  __shared__ __align__(16) float          ldsS[12288];   // 8 waves x 6KB: hp 4 rows | he 8 rows
  const int t    = threadIdx.x;       // 0..511
  const int lane = t & 63;
  const int wid  = t >> 6;            // 0..7
  const int r    = lane & 15;         // tile row within group / GEMM2 out-row lane
  const int o    = lane >> 4;         // k-octet / out-col-quad selector
  const int Rr   = r & 7;             // he row
  const int swzR = Rr << 4;

  // ---- stage W2 frag table (once per block) ----
  for (int i = t; i < 2048; i += 512)
    ((uint4*)ldsW)[i] = ((const uint4*)w2f)[i];
  __syncthreads();                    // the only barrier

  // W3 fragments (A-slot), loop-invariant
  short8 w3r[4];
  #pragma unroll
  for (int ks = 0; ks < 4; ++ks)
    w3r[ks] = *(const short8*)(w3f + (ks * 64 + lane) * 8);
  const f32x4v b3v = *(const f32x4v*)(b3 + o * 4);
  const float* b2o = b2 + 8 * o;

  char* Sb = (char*)(ldsS + wid * 1536);

  // he staging: pre-swizzled source offsets (involution: byte w holds he[row][w ^ (row<<4)])
  int heoff[4];
  #pragma unroll
  for (int i = 0; i < 4; ++i) {
    const int row = 2 * i + (lane >> 5);
    heoff[i] = row * 512 + ((((lane & 31) * 16)) ^ (row << 4));
  }

  #define STAGE(b0_, e0_) do { \
    glds16(hp + (b0_) * 128 + lane * 4,       Sb); \
    glds16(hp + (b0_) * 128 + 256 + lane * 4, Sb + 1024); \
    _Pragma("unroll") \
    for (int i_ = 0; i_ < 4; ++i_) \
      glds16((const char*)he + (e0_) * 512 + heoff[i_], Sb + 2048 + i_ * 1024); \
  } while (0)

  int tile = blockIdx.x * 8 + wid;    // r17's natural stride-4096 assignment (proven fastest)
  {
    const int tbp = (int)(((unsigned)tile * 5243u) >> 18);  // tile/50 exact for tile<25600
    const int te  = tile - tbp * 50;
    STAGE(tbp * 4, te * 8);
  }
  asm volatile("s_waitcnt vmcnt(0)" ::: "memory");
  __builtin_amdgcn_sched_barrier(0);

  const char* heB = Sb + 2048 + Rr * 512;
  const char* hA  = Sb + (r >> 3) * 512;
  const char* hB  = hA + 1024;

  while (true) {
    const int tbp = (int)(((unsigned)tile * 5243u) >> 18);
    const int te  = tile - tbp * 50;
    const int b0  = tbp * 4;
    const int e0  = te * 8;

    // ---- acc init = b2 fragment (folds bias into MFMA C-input) ----
    f32x4v acc0[8], acc1[8];
    #pragma unroll
    for (int g = 0; g < 8; ++g) {
      const f32x4v bv = *(const f32x4v*)(b2o + 32 * (g >> 1) + 4 * (g & 1));
      acc0[g] = bv; acc1[g] = bv;
    }

    // ---- fused BUILD + GEMM1 (independent per-element silu) ----
    #pragma unroll
    for (int ks = 0; ks < 4; ++ks) {
      const int x = ks * 128 + o * 32;
      const f32x4v ge0 = *(const f32x4v*)(heB + ((x)      ^ swzR));
      const f32x4v ge1 = *(const f32x4v*)(heB + ((x + 16) ^ swzR));
      const f32x4v a0  = *(const f32x4v*)(hA + x);
      const f32x4v a1  = *(const f32x4v*)(hA + x + 16);
      const f32x4v c0  = *(const f32x4v*)(hB + x);
      const f32x4v c1  = *(const f32x4v*)(hB + x + 16);
      const f32x4v xA0 = a0 + ge0, xA1 = a1 + ge1;
      const f32x4v xB0 = c0 + ge0, xB1 = c1 + ge1;
      f32x4v dA0, dA1, dB0, dB1;
      #pragma unroll
      for (int j = 0; j < 4; ++j) {
        dA0[j] = __builtin_amdgcn_exp2f(xA0[j] * -1.44269504f);
        dA1[j] = __builtin_amdgcn_exp2f(xA1[j] * -1.44269504f);
        dB0[j] = __builtin_amdgcn_exp2f(xB0[j] * -1.44269504f);
        dB1[j] = __builtin_amdgcn_exp2f(xB1[j] * -1.44269504f);
      }
      dA0 += 1.0f; dA1 += 1.0f; dB0 += 1.0f; dB1 += 1.0f;
      f32x4v sA0, sA1, sB0, sB1;
      #pragma unroll
      for (int j = 0; j < 4; ++j) {
        sA0[j] = __builtin_amdgcn_rcpf(dA0[j]); sA1[j] = __builtin_amdgcn_rcpf(dA1[j]);
        sB0[j] = __builtin_amdgcn_rcpf(dB0[j]); sB1[j] = __builtin_amdgcn_rcpf(dB1[j]);
      }
      sA0 *= xA0; sA1 *= xA1; sB0 *= xB0; sB1 *= xB1;
      short8 fA, fB;
      #pragma unroll
      for (int j = 0; j < 4; ++j) {
        fA[j] = (short)bf16c(sA0[j]); fA[4 + j] = (short)bf16c(sA1[j]);
        fB[j] = (short)bf16c(sB0[j]); fB[4 + j] = (short)bf16c(sB1[j]);
      }
      __builtin_amdgcn_s_setprio(1);
      #pragma unroll
      for (int g = 0; g < 8; ++g) {
        const short8 wf = *(const short8*)((const char*)ldsW + (((g * 4 + ks) << 10) | (lane << 4)));
        acc0[g] = __builtin_amdgcn_mfma_f32_16x16x32_bf16(wf, fA, acc0[g], 0, 0, 0);
        acc1[g] = __builtin_amdgcn_mfma_f32_16x16x32_bf16(wf, fB, acc1[g], 0, 0, 0);
      }
      __builtin_amdgcn_s_setprio(0);
    }

    // ---- stage next tile (slab reads all retired; glds lands under WB/GEMM2/stores) ----
    asm volatile("s_waitcnt lgkmcnt(0)" ::: "memory");
    __builtin_amdgcn_sched_barrier(0);
    const int nxt = tile + NWAVES;
    if (nxt < NT) {
      const int ntbp = (int)(((unsigned)nxt * 5243u) >> 18);
      const int nte  = nxt - ntbp * 50;
      STAGE(ntbp * 4, nte * 8);
    }
    __builtin_amdgcn_sched_barrier(0);

    // ---- per row-group: WB-silu (independent rcp) -> bfrag2 -> GEMM2 -> nt store ----
    #pragma unroll
    for (int G = 0; G < 2; ++G) {
      short8 bf2[4];
      #pragma unroll
      for (int ks2 = 0; ks2 < 4; ++ks2) {
        const f32x4v y0 = G ? acc1[2 * ks2]     : acc0[2 * ks2];
        const f32x4v y1 = G ? acc1[2 * ks2 + 1] : acc0[2 * ks2 + 1];
        f32x4v d0, d1;
        #pragma unroll
        for (int j = 0; j < 4; ++j) {
          d0[j] = __builtin_amdgcn_exp2f(y0[j] * -1.44269504f);
          d1[j] = __builtin_amdgcn_exp2f(y1[j] * -1.44269504f);
        }
        d0 += 1.0f; d1 += 1.0f;
        f32x4v s0, s1;
        #pragma unroll
        for (int j = 0; j < 4; ++j) {
          s0[j] = __builtin_amdgcn_rcpf(d0[j]); s1[j] = __builtin_amdgcn_rcpf(d1[j]);
        }
        s0 *= y0; s1 *= y1;
        #pragma unroll
        for (int j = 0; j < 4; ++j) {
          bf2[ks2][j]     = (short)bf16c(s0[j]);
          bf2[ks2][4 + j] = (short)bf16c(s1[j]);
        }
      }
      f32x4v acc2 = {};
      __builtin_amdgcn_s_setprio(1);
      #pragma unroll
      for (int ks2 = 0; ks2 < 4; ++ks2)
        acc2 = __builtin_amdgcn_mfma_f32_16x16x32_bf16(w3r[ks2], bf2[ks2], acc2, 0, 0, 0);
      __builtin_amdgcn_s_setprio(0);

      const int grow = (b0 + G * 2 + (r >> 3)) * 400 + e0 + Rr;
      f32x4v ov = acc2 + b3v;
      __builtin_nontemporal_store(ov, (f32x4v*)(out + grow * 16 + o * 4));
    }

    if (nxt >= NT) break;
    tile = nxt;
    // staged S(t+1) ready: 6 glds older than the 2 stores -> vmcnt(2) drains all glds
    asm volatile("s_waitcnt vmcnt(2)" ::: "memory");
    __builtin_amdgcn_sched_barrier(0);
  }
  #undef STAGE
}

extern "C" void kernel_launch(void* const* d_in, const int* in_sizes, int n_in,
                              void* d_out, int out_size, void* d_ws, size_t ws_size,
                              hipStream_t stream) {
  const int*   z_j    = (const int*)d_in[0];
  const int*   z_k    = (const int*)d_in[1];
  const float* e_feat = (const float*)d_in[2];
  const float* z_emb  = (const float*)d_in[3];
  const float* W1     = (const float*)d_in[4];
  const float* b1     = (const float*)d_in[5];
  const float* W2     = (const float*)d_in[6];
  const float* b2     = (const float*)d_in[7];
  const float* W3     = (const float*)d_in[8];
  const float* b3     = (const float*)d_in[9];
  float* out = (float*)d_out;
  char*  ws  = (char*)d_ws;

  float*          hp   = (float*)(ws);                     // 1 MB
  float*          he   = (float*)(ws + 0x100000);          // 200 KB
  unsigned short* w2f  = (unsigned short*)(ws + 0x140000); // 32 KB
  unsigned short* w3f  = (unsigned short*)(ws + 0x148000); // 4 KB

  hipLaunchKernelGGL(prep_all, dim3(BPn + NEn + 128), dim3(128), 0, stream,
                     z_j, z_k, e_feat, z_emb, W1, b1, W2, W3, hp, he, w2f, w3f);
  hipLaunchKernelGGL(fused_main, dim3(NBLK), dim3(512), 0, stream,
                     hp, he, w2f, w3f, b2, b3, out);
}